// Round 1
// baseline (432.668 us; speedup 1.0000x reference)
//
#include <hip/hip_runtime.h>
#include <hip/hip_bf16.h>

// MaskMLP R5: register-streamed weights in modules_fused.
// Key observation: in P1..P4 each wave consumes a DISJOINT set of weight rows
// (rn = w*32 + j*16 + ln), so LDS-staging W was pure overhead. Weights now load
// straight to VGPRs (dist-2 software pipeline, compiler-managed vmcnt); only
// the activations h0..h3 (shared across waves) live in LDS, XOR-swizzled.
// Barriers per block: ~80 -> 5. LDS 64KB -> 48KB => 3 blocks/CU.
// gemm_l0 / cvt_all unchanged from R4.

using bf16 = __hip_bfloat16;
typedef short bf16x8 __attribute__((ext_vector_type(8)));   // 8 bf16 = 4 VGPRs
typedef float f32x4 __attribute__((ext_vector_type(4)));

constexpr int B_ = 1024;   // batch
constexpr int M_ = 128;    // modules

// raw waits/barrier: memory clobber stops the compiler moving LDS/global ops
// across them; s_waitcnt mnemonic leaves unmentioned counters at no-wait.
#define WAITV(N) asm volatile("s_waitcnt vmcnt(" #N ")" ::: "memory")
#define WAITL()  asm volatile("s_waitcnt lgkmcnt(0)" ::: "memory")
#define BAR()    asm volatile("s_barrier" ::: "memory")

// async global->LDS, 16B/lane; LDS dest = wave-uniform base + lane*16.
__device__ __forceinline__ void gload16_lds(const bf16* gp, bf16* lp) {
    __builtin_amdgcn_global_load_lds(
        (__attribute__((address_space(1))) void*)const_cast<bf16*>(gp),
        (__attribute__((address_space(3))) void*)lp,
        16, 0, 0);
}

// ---------------- fused fp32 -> bf16 conversion (x, W0..W4) ----------------
struct CvtArgs {
    const float4* src[6];
    short4* dst[6];
};
__global__ void cvt_all(CvtArgs a) {
    constexpr int starts[7] = {0, 1048576, 5242880, 5308416, 5570560,
                               6619136, 10813440};
    int i = blockIdx.x * blockDim.x + threadIdx.x;
    if (i >= starts[6]) return;
    int s = 0;
#pragma unroll
    for (int k = 1; k < 6; ++k) s += (i >= starts[k]) ? 1 : 0;
    int off = i - starts[s];
    float4 v = a.src[s][off];
    union { bf16 h[4]; short4 s4; } u;
    u.h[0] = __float2bfloat16(v.x);
    u.h[1] = __float2bfloat16(v.y);
    u.h[2] = __float2bfloat16(v.z);
    u.h[3] = __float2bfloat16(v.w);
    a.dst[s][off] = u.s4;
}

// ---------------- L0: h0 = relu(x @ W0^T + b0), K=4096 ----------------
// 128x64 tile, BK=64 (two 32-k halves per stage), 2 LDS sets, prefetch dist 2.
__global__ __launch_bounds__(256, 2)
void gemm_l0(const bf16* __restrict__ A, const bf16* __restrict__ W,
             const float* __restrict__ bias, bf16* __restrict__ C) {
    constexpr int LDA = 4096;
    __shared__ __align__(16) bf16 sA[2][2][128 * 32];   // [set][half][row*32]
    __shared__ __align__(16) bf16 sB[2][2][64 * 32];

    const int tid = threadIdx.x, w = tid >> 6, lane = tid & 63;
    const int q = lane >> 4, ln = lane & 15;
    const int lr = lane >> 2, lk = lane & 3;
    const int swz = (lk ^ (lr & 3)) * 8;
    const int wm = w >> 1, wn = w & 1;
    const int r0 = blockIdx.y * 128, c0 = blockIdx.x * 64;

    auto stage = [&](int s, int set) {   // 6 gloads/wave
        const int k0 = s * 64;
#pragma unroll
        for (int h = 0; h < 2; ++h) {
#pragma unroll
            for (int t = 0; t < 2; ++t) {
                int grp = w * 2 + t;
                gload16_lds(A + (size_t)(r0 + grp * 16 + lr) * LDA + k0 + h * 32 + swz,
                            &sA[set][h][grp * 512]);
            }
            gload16_lds(W + (size_t)(c0 + w * 16 + lr) * LDA + k0 + h * 32 + swz,
                        &sB[set][h][w * 512]);
        }
    };

    f32x4 acc[4][2];
#pragma unroll
    for (int i = 0; i < 4; ++i)
#pragma unroll
        for (int j = 0; j < 2; ++j) acc[i][j] = (f32x4){0.f, 0.f, 0.f, 0.f};

    stage(0, 0);
    stage(1, 1);
    for (int r = 0; r < 64; ++r) {
        if (r < 63) WAITV(6); else WAITV(0);   // current stage arrived
        BAR();
        const int set = r & 1;
        bf16x8 aF[2][4], bF[2][2];
#pragma unroll
        for (int h = 0; h < 2; ++h) {
#pragma unroll
            for (int i = 0; i < 4; ++i) {
                int row = wm * 64 + i * 16 + ln;
                aF[h][i] = *(const bf16x8*)&sA[set][h][row * 32 + ((q ^ (row & 3)) * 8)];
            }
#pragma unroll
            for (int j = 0; j < 2; ++j) {
                int rn = wn * 32 + j * 16 + ln;
                bF[h][j] = *(const bf16x8*)&sB[set][h][rn * 32 + ((q ^ (rn & 3)) * 8)];
            }
        }
        WAITL();
        BAR();                                  // release this set
        if (r + 2 < 64) stage(r + 2, set);      // refill just-freed set
#pragma unroll
        for (int h = 0; h < 2; ++h)
#pragma unroll
            for (int i = 0; i < 4; ++i)
#pragma unroll
                for (int j = 0; j < 2; ++j)
                    acc[i][j] = __builtin_amdgcn_mfma_f32_16x16x32_bf16(
                        aF[h][i], bF[h][j], acc[i][j], 0, 0, 0);
    }

#pragma unroll
    for (int j = 0; j < 2; ++j) {
        int col = c0 + wn * 32 + j * 16 + ln;
        float bv = bias[col];
#pragma unroll
        for (int i = 0; i < 4; ++i)
#pragma unroll
            for (int rr = 0; rr < 4; ++rr) {
                int row = r0 + wm * 64 + i * 16 + q * 4 + rr;
                float v = acc[i][j][rr] + bv;
                v = v > 0.f ? v : 0.f;
                C[(size_t)row * 4096 + col] = __float2bfloat16(v);
            }
    }
}

// ---------------- fused L1..L4 + Wout + sigmoid ----------------
// grid (16 strips, 128 modules), 4 waves, 3 blocks/CU (48KB LDS).
// LDS pool (bf16 elems) -- ACTIVATIONS ONLY:
//   h3 [0,16384)     xor32  (P3->P4), overlays h1/h0 (dead by P3 epilogue)
//   h1 [0,4096)      xor8   (P1->P2)
//   h0 [4096,6144)   xor-col (gload_lds pre-swizzled, ->P1)
//   h2 [16384,24576) xor16  (P2->P3); float scratch reuses this after P4
// Weights W1..W4 never touch LDS: each wave's B-fragment rows are private,
// loaded global->VGPR with a dist-2 rotating 2x2 fragment buffer.
__global__ __launch_bounds__(256, 3)
void modules_fused(const bf16* __restrict__ h0g,
                   const bf16* __restrict__ W1b, const float* __restrict__ b1,
                   const bf16* __restrict__ W2b, const float* __restrict__ b2,
                   const bf16* __restrict__ W3b, const float* __restrict__ b3,
                   const bf16* __restrict__ W4b, const float* __restrict__ b4,
                   const float* __restrict__ Wout, const float* __restrict__ bout,
                   float* __restrict__ out) {
    constexpr int H3 = 0, H1 = 0, H0 = 4096, H2 = 16384;
    __shared__ __align__(16) bf16 pool[24576];

    const int tid = threadIdx.x, w = tid >> 6, lane = tid & 63;
    const int q = lane >> 4, ln = lane & 15;
    const int lr = lane >> 2, lk = lane & 3;
    const int swz = (lk ^ (lr & 3)) * 8;
    const int m = blockIdx.y;
    const int r0 = blockIdx.x * 64;

    const bf16* W1m = W1b + (size_t)m * 64 * 32;
    const bf16* W2m = W2b + (size_t)m * 128 * 64;
    const bf16* W3m = W3b + (size_t)m * 256 * 128;
    const bf16* W4m = W4b + (size_t)m * 512 * 256;

    // XOR-chunk activation layout: elem = row*nch*8 + ((chunk^(row&7))*8)+sub.
    // For b128 fragment reads (16 ln-rows x 4 q-slots) this gives the wave64
    // minimum of 8 lanes per 4-bank group (conflict-free for ds_read_b128).
    auto rdX = [&](int base, int nch, int row, int chunk) -> bf16x8 {
        return *(const bf16x8*)&pool[base + row * nch * 8 + ((chunk ^ (row & 7)) * 8)];
    };
    auto rdA0 = [&](int row) -> bf16x8 {   // h0: gload pre-swizzle layout
        return *(const bf16x8*)&pool[H0 + row * 32 + ((q ^ (row & 3)) * 8)];
    };
    auto wrX = [&](int base, int nch, int row, int col, float v) {
        pool[base + row * nch * 8 + (((col >> 3) ^ (row & 7)) * 8) + (col & 7)] =
            __float2bfloat16(v);
    };
    // weight B-fragment straight from global: lane(q,ln) gets W[row][kc*8..+8]
    auto ldW = [&](const bf16* Wm, int ldg, int row, int kc) -> bf16x8 {
        return *(const bf16x8*)&Wm[(size_t)row * ldg + kc * 8];
    };

    // ---- epilogue scalars (drained by the WAITV(0) below)
    float b1v = b1[m * 64 + w * 16 + ln];
    float b2v[2], b3v[2][2], b4v[4][2], wov[4][2];
#pragma unroll
    for (int j = 0; j < 2; ++j) b2v[j] = b2[m * 128 + w * 32 + j * 16 + ln];
#pragma unroll
    for (int oc = 0; oc < 2; ++oc)
#pragma unroll
        for (int j = 0; j < 2; ++j)
            b3v[oc][j] = b3[m * 256 + oc * 128 + w * 32 + j * 16 + ln];
#pragma unroll
    for (int nc = 0; nc < 4; ++nc)
#pragma unroll
        for (int j = 0; j < 2; ++j) {
            int col = nc * 128 + w * 32 + j * 16 + ln;
            b4v[nc][j] = b4[(size_t)m * 512 + col];
            wov[nc][j] = Wout[(size_t)m * 512 + col];
        }
    float boutv = bout[m];

    // ---- h0 strip -> LDS (the only shared input); W1/W2 + W3 r0,r1 -> regs
    gload16_lds(h0g + (size_t)(r0 + w * 16 + lr) * 4096 + m * 32 + swz,
                pool + H0 + w * 512);
    bf16x8 f1 = ldW(W1m, 32, w * 16 + ln, q);
    bf16x8 f2[2][2], f3[2][2], f4[2][2];
#pragma unroll
    for (int kk = 0; kk < 2; ++kk)
#pragma unroll
        for (int j = 0; j < 2; ++j)
            f2[kk][j] = ldW(W2m, 64, w * 32 + j * 16 + ln, kk * 4 + q);
#pragma unroll
    for (int p = 0; p < 2; ++p)
#pragma unroll
        for (int j = 0; j < 2; ++j)
            f3[p][j] = ldW(W3m, 128, w * 32 + j * 16 + ln, p * 4 + q);
    WAITV(0);
    BAR();   // h0 visible to all waves

    // ================= P1: h1 = relu(h0 @ W1^T + b1) =================
    {
        f32x4 a1[4];
#pragma unroll
        for (int i = 0; i < 4; ++i) {
            a1[i] = (f32x4){0.f, 0.f, 0.f, 0.f};
            a1[i] = __builtin_amdgcn_mfma_f32_16x16x32_bf16(rdA0(i * 16 + ln), f1,
                                                            a1[i], 0, 0, 0);
        }
#pragma unroll
        for (int i = 0; i < 4; ++i)
#pragma unroll
            for (int rr = 0; rr < 4; ++rr) {
                float v = a1[i][rr] + b1v;
                wrX(H1, 8, i * 16 + q * 4 + rr, w * 16 + ln, v > 0.f ? v : 0.f);
            }
        WAITL();
        BAR();   // h1 visible
    }

    // ================= P2: h2 = relu(h1 @ W2^T + b2) =================
    {
        f32x4 a2[4][2];
#pragma unroll
        for (int i = 0; i < 4; ++i)
#pragma unroll
            for (int j = 0; j < 2; ++j) a2[i][j] = (f32x4){0.f, 0.f, 0.f, 0.f};
#pragma unroll
        for (int kk = 0; kk < 2; ++kk) {
            bf16x8 aF[4];
#pragma unroll
            for (int i = 0; i < 4; ++i) aF[i] = rdX(H1, 8, i * 16 + ln, kk * 4 + q);
#pragma unroll
            for (int i = 0; i < 4; ++i)
#pragma unroll
                for (int j = 0; j < 2; ++j)
                    a2[i][j] = __builtin_amdgcn_mfma_f32_16x16x32_bf16(
                        aF[i], f2[kk][j], a2[i][j], 0, 0, 0);
        }
#pragma unroll
        for (int j = 0; j < 2; ++j)
#pragma unroll
            for (int i = 0; i < 4; ++i)
#pragma unroll
                for (int rr = 0; rr < 4; ++rr) {
                    float v = a2[i][j][rr] + b2v[j];
                    wrX(H2, 16, i * 16 + q * 4 + rr, w * 32 + j * 16 + ln,
                        v > 0.f ? v : 0.f);
                }
        WAITL();
        BAR();   // h2 visible
    }

    // ===== P3: h3 = relu(h2 @ W3^T + b3); W3 reg-stream dist-2, NO bars =====
    // (h2 read-only; h3 writes are w-partitioned; h1/h0 under h3 are dead
    //  for ALL waves -- they passed the P2-end barrier.)
#pragma unroll
    for (int oc = 0; oc < 2; ++oc) {
        f32x4 a3[4][2];
#pragma unroll
        for (int i = 0; i < 4; ++i)
#pragma unroll
            for (int j = 0; j < 2; ++j) a3[i][j] = (f32x4){0.f, 0.f, 0.f, 0.f};
#pragma unroll
        for (int kr = 0; kr < 4; ++kr) {
            const int r = oc * 4 + kr, p = r & 1;
            bf16x8 c0 = f3[p][0], c1 = f3[p][1];
            if (r + 2 < 8) {
                const int r2 = r + 2;
#pragma unroll
                for (int j = 0; j < 2; ++j)
                    f3[p][j] = ldW(W3m, 128,
                                   (r2 >> 2) * 128 + w * 32 + j * 16 + ln,
                                   (r2 & 3) * 4 + q);
            }
            bf16x8 aF[4];
#pragma unroll
            for (int i = 0; i < 4; ++i) aF[i] = rdX(H2, 16, i * 16 + ln, kr * 4 + q);
#pragma unroll
            for (int i = 0; i < 4; ++i) {
                a3[i][0] = __builtin_amdgcn_mfma_f32_16x16x32_bf16(aF[i], c0,
                                                                   a3[i][0], 0, 0, 0);
                a3[i][1] = __builtin_amdgcn_mfma_f32_16x16x32_bf16(aF[i], c1,
                                                                   a3[i][1], 0, 0, 0);
            }
        }
#pragma unroll
        for (int j = 0; j < 2; ++j)
#pragma unroll
            for (int i = 0; i < 4; ++i)
#pragma unroll
                for (int rr = 0; rr < 4; ++rr) {
                    float v = a3[i][j][rr] + b3v[oc][j];
                    wrX(H3, 32, i * 16 + q * 4 + rr,
                        oc * 128 + w * 32 + j * 16 + ln, v > 0.f ? v : 0.f);
                }
    }
    // prime W4 rounds 0,1 (VGPR dest: safe to stay in flight across the bar)
#pragma unroll
    for (int p = 0; p < 2; ++p)
#pragma unroll
        for (int j = 0; j < 2; ++j)
            f4[p][j] = ldW(W4m, 256, w * 32 + j * 16 + ln, p * 4 + q);
    WAITL();
    BAR();   // h3 visible; h2 dead for all waves

    // == P4: L4 (4 nc-chunks of 128 cols) + Wout dot; dist-2, ZERO barriers ==
    float pl[4][4];
#pragma unroll
    for (int i = 0; i < 4; ++i)
#pragma unroll
        for (int rr = 0; rr < 4; ++rr) pl[i][rr] = 0.f;

#pragma unroll
    for (int nc = 0; nc < 4; ++nc) {
        f32x4 a4[4][2];
#pragma unroll
        for (int i = 0; i < 4; ++i)
#pragma unroll
            for (int j = 0; j < 2; ++j) a4[i][j] = (f32x4){0.f, 0.f, 0.f, 0.f};
#pragma unroll
        for (int kr = 0; kr < 8; ++kr) {
            const int r = nc * 8 + kr, p = r & 1;
            bf16x8 c0 = f4[p][0], c1 = f4[p][1];
            if (r + 2 < 32) {
                const int r2 = r + 2;
#pragma unroll
                for (int j = 0; j < 2; ++j)
                    f4[p][j] = ldW(W4m, 256,
                                   (r2 >> 3) * 128 + w * 32 + j * 16 + ln,
                                   (r2 & 7) * 4 + q);
            }
            bf16x8 aF[4];
#pragma unroll
            for (int i = 0; i < 4; ++i) aF[i] = rdX(H3, 32, i * 16 + ln, kr * 4 + q);
#pragma unroll
            for (int i = 0; i < 4; ++i) {
                a4[i][0] = __builtin_amdgcn_mfma_f32_16x16x32_bf16(aF[i], c0,
                                                                   a4[i][0], 0, 0, 0);
                a4[i][1] = __builtin_amdgcn_mfma_f32_16x16x32_bf16(aF[i], c1,
                                                                   a4[i][1], 0, 0, 0);
            }
        }
#pragma unroll
        for (int j = 0; j < 2; ++j) {
            float bb = b4v[nc][j], wv = wov[nc][j];
#pragma unroll
            for (int i = 0; i < 4; ++i)
#pragma unroll
                for (int rr = 0; rr < 4; ++rr) {
                    float v = a4[i][j][rr] + bb;
                    v = v > 0.f ? v : 0.f;
                    pl[i][rr] += v * wv;
                }
        }
    }

    // ---- reduce: 16 col-lanes via shuffle, 4 waves via LDS, sigmoid store ----
    // scratch over dead h2 [16384..): lagging waves only read h3 [0,16384).
    float* sc = (float*)&pool[H2];
#pragma unroll
    for (int i = 0; i < 4; ++i)
#pragma unroll
        for (int rr = 0; rr < 4; ++rr) {
            float p = pl[i][rr];
            p += __shfl_xor(p, 1);
            p += __shfl_xor(p, 2);
            p += __shfl_xor(p, 4);
            p += __shfl_xor(p, 8);
            if (ln == 0) sc[w * 64 + i * 16 + q * 4 + rr] = p;
        }
    __syncthreads();
    if (tid < 64) {
        float s = sc[tid] + sc[64 + tid] + sc[128 + tid] + sc[192 + tid];
        float lg = s + boutv;
        out[(size_t)(r0 + tid) * M_ + m] = 1.f / (1.f + __expf(-lg));
    }
}

// ---------------- host ----------------
extern "C" void kernel_launch(void* const* d_in, const int* in_sizes, int n_in,
                              void* d_out, int out_size, void* d_ws, size_t ws_size,
                              hipStream_t stream) {
    const float* x    = (const float*)d_in[0];
    const float* W0   = (const float*)d_in[1];
    const float* b0   = (const float*)d_in[2];
    const float* W1   = (const float*)d_in[3];
    const float* b1   = (const float*)d_in[4];
    const float* W2   = (const float*)d_in[5];
    const float* b2   = (const float*)d_in[6];
    const float* W3   = (const float*)d_in[7];
    const float* b3   = (const float*)d_in[8];
    const float* W4   = (const float*)d_in[9];
    const float* b4   = (const float*)d_in[10];
    const float* Wout = (const float*)d_in[11];
    const float* bout = (const float*)d_in[12];
    float* out = (float*)d_out;

    char* ws = (char*)d_ws;
    size_t off = 0;
    auto alloc = [&](size_t bytes) -> void* {
        off = (off + 255) & ~(size_t)255;
        void* p = ws + off;
        off += bytes;
        return p;
    };
    bf16* W0b = (bf16*)alloc((size_t)4096 * 4096 * 2);
    bf16* W1b = (bf16*)alloc((size_t)M_ * 64 * 32 * 2);
    bf16* W2b = (bf16*)alloc((size_t)M_ * 128 * 64 * 2);
    bf16* W3b = (bf16*)alloc((size_t)M_ * 256 * 128 * 2);
    bf16* W4b = (bf16*)alloc((size_t)M_ * 512 * 256 * 2);
    bf16* xb  = (bf16*)alloc((size_t)B_ * 4096 * 2);
    bf16* h0  = (bf16*)alloc((size_t)B_ * 4096 * 2);   // [B][128][32]

    CvtArgs ca;
    ca.src[0] = (const float4*)x;  ca.dst[0] = (short4*)xb;
    ca.src[1] = (const float4*)W0; ca.dst[1] = (short4*)W0b;
    ca.src[2] = (const float4*)W1; ca.dst[2] = (short4*)W1b;
    ca.src[3] = (const float4*)W2; ca.dst[3] = (short4*)W2b;
    ca.src[4] = (const float4*)W3; ca.dst[4] = (short4*)W3b;
    ca.src[5] = (const float4*)W4; ca.dst[5] = (short4*)W4b;
    cvt_all<<<(10813440 + 255) / 256, 256, 0, stream>>>(ca);

    {
        dim3 g(4096 / 64, B_ / 128, 1);
        gemm_l0<<<g, 256, 0, stream>>>(xb, W0b, b0, h0);
    }
    {
        dim3 g(B_ / 64, M_, 1);
        modules_fused<<<g, 256, 0, stream>>>(h0, W1b, b1, W2b, b2, W3b, b3,
                                             W4b, b4, Wout, bout, out);
    }
}

// Round 2
// 340.027 us; speedup vs baseline: 1.2725x; 1.2725x over previous
//
#include <hip/hip_runtime.h>
#include <hip/hip_bf16.h>

// MaskMLP R6: R5's register-streamed weights + per-round vmcnt fences.
// R5 post-mortem: removing all fences let the scheduler hoist every W-prefetch
// load -> ~240 VGPRs of pending results -> accumulator spill (307MB scratch
// writes, 2.3x slowdown). R6 pins the pipeline at dist-2 with a memory-
// clobbered s_waitcnt vmcnt(2) per round (the T3/T4 discipline), bounding
// in-flight W data to 16 VGPRs. Structure otherwise identical to R5:
//   - W1..W4 global->VGPR (wave-private rows; no LDS staging, no W barriers)
//   - activations h0..h3 in 48KB LDS, XOR-swizzled => 3 blocks/CU
//   - 5 barriers per block total (h0/h1/h2/h3/reduce)
// gemm_l0 / cvt_all unchanged.

using bf16 = __hip_bfloat16;
typedef short bf16x8 __attribute__((ext_vector_type(8)));   // 8 bf16 = 4 VGPRs
typedef float f32x4 __attribute__((ext_vector_type(4)));

constexpr int B_ = 1024;   // batch
constexpr int M_ = 128;    // modules

// raw waits/barrier: memory clobber stops the compiler moving LDS/global ops
// across them; s_waitcnt mnemonic leaves unmentioned counters at no-wait.
#define WAITV(N) asm volatile("s_waitcnt vmcnt(" #N ")" ::: "memory")
#define WAITL()  asm volatile("s_waitcnt lgkmcnt(0)" ::: "memory")
#define BAR()    asm volatile("s_barrier" ::: "memory")
#define CFENCE() asm volatile("" ::: "memory")   // compiler-only ordering wall

// async global->LDS, 16B/lane; LDS dest = wave-uniform base + lane*16.
__device__ __forceinline__ void gload16_lds(const bf16* gp, bf16* lp) {
    __builtin_amdgcn_global_load_lds(
        (__attribute__((address_space(1))) void*)const_cast<bf16*>(gp),
        (__attribute__((address_space(3))) void*)lp,
        16, 0, 0);
}

// ---------------- fused fp32 -> bf16 conversion (x, W0..W4) ----------------
struct CvtArgs {
    const float4* src[6];
    short4* dst[6];
};
__global__ void cvt_all(CvtArgs a) {
    constexpr int starts[7] = {0, 1048576, 5242880, 5308416, 5570560,
                               6619136, 10813440};
    int i = blockIdx.x * blockDim.x + threadIdx.x;
    if (i >= starts[6]) return;
    int s = 0;
#pragma unroll
    for (int k = 1; k < 6; ++k) s += (i >= starts[k]) ? 1 : 0;
    int off = i - starts[s];
    float4 v = a.src[s][off];
    union { bf16 h[4]; short4 s4; } u;
    u.h[0] = __float2bfloat16(v.x);
    u.h[1] = __float2bfloat16(v.y);
    u.h[2] = __float2bfloat16(v.z);
    u.h[3] = __float2bfloat16(v.w);
    a.dst[s][off] = u.s4;
}

// ---------------- L0: h0 = relu(x @ W0^T + b0), K=4096 ----------------
// 128x64 tile, BK=64 (two 32-k halves per stage), 2 LDS sets, prefetch dist 2.
__global__ __launch_bounds__(256, 2)
void gemm_l0(const bf16* __restrict__ A, const bf16* __restrict__ W,
             const float* __restrict__ bias, bf16* __restrict__ C) {
    constexpr int LDA = 4096;
    __shared__ __align__(16) bf16 sA[2][2][128 * 32];   // [set][half][row*32]
    __shared__ __align__(16) bf16 sB[2][2][64 * 32];

    const int tid = threadIdx.x, w = tid >> 6, lane = tid & 63;
    const int q = lane >> 4, ln = lane & 15;
    const int lr = lane >> 2, lk = lane & 3;
    const int swz = (lk ^ (lr & 3)) * 8;
    const int wm = w >> 1, wn = w & 1;
    const int r0 = blockIdx.y * 128, c0 = blockIdx.x * 64;

    auto stage = [&](int s, int set) {   // 6 gloads/wave
        const int k0 = s * 64;
#pragma unroll
        for (int h = 0; h < 2; ++h) {
#pragma unroll
            for (int t = 0; t < 2; ++t) {
                int grp = w * 2 + t;
                gload16_lds(A + (size_t)(r0 + grp * 16 + lr) * LDA + k0 + h * 32 + swz,
                            &sA[set][h][grp * 512]);
            }
            gload16_lds(W + (size_t)(c0 + w * 16 + lr) * LDA + k0 + h * 32 + swz,
                        &sB[set][h][w * 512]);
        }
    };

    f32x4 acc[4][2];
#pragma unroll
    for (int i = 0; i < 4; ++i)
#pragma unroll
        for (int j = 0; j < 2; ++j) acc[i][j] = (f32x4){0.f, 0.f, 0.f, 0.f};

    stage(0, 0);
    stage(1, 1);
    for (int r = 0; r < 64; ++r) {
        if (r < 63) WAITV(6); else WAITV(0);   // current stage arrived
        BAR();
        const int set = r & 1;
        bf16x8 aF[2][4], bF[2][2];
#pragma unroll
        for (int h = 0; h < 2; ++h) {
#pragma unroll
            for (int i = 0; i < 4; ++i) {
                int row = wm * 64 + i * 16 + ln;
                aF[h][i] = *(const bf16x8*)&sA[set][h][row * 32 + ((q ^ (row & 3)) * 8)];
            }
#pragma unroll
            for (int j = 0; j < 2; ++j) {
                int rn = wn * 32 + j * 16 + ln;
                bF[h][j] = *(const bf16x8*)&sB[set][h][rn * 32 + ((q ^ (rn & 3)) * 8)];
            }
        }
        WAITL();
        BAR();                                  // release this set
        if (r + 2 < 64) stage(r + 2, set);      // refill just-freed set
#pragma unroll
        for (int h = 0; h < 2; ++h)
#pragma unroll
            for (int i = 0; i < 4; ++i)
#pragma unroll
                for (int j = 0; j < 2; ++j)
                    acc[i][j] = __builtin_amdgcn_mfma_f32_16x16x32_bf16(
                        aF[h][i], bF[h][j], acc[i][j], 0, 0, 0);
    }

#pragma unroll
    for (int j = 0; j < 2; ++j) {
        int col = c0 + wn * 32 + j * 16 + ln;
        float bv = bias[col];
#pragma unroll
        for (int i = 0; i < 4; ++i)
#pragma unroll
            for (int rr = 0; rr < 4; ++rr) {
                int row = r0 + wm * 64 + i * 16 + q * 4 + rr;
                float v = acc[i][j][rr] + bv;
                v = v > 0.f ? v : 0.f;
                C[(size_t)row * 4096 + col] = __float2bfloat16(v);
            }
    }
}

// ---------------- fused L1..L4 + Wout + sigmoid ----------------
// grid (16 strips, 128 modules), 4 waves, 3 blocks/CU (48KB LDS).
// LDS pool (bf16 elems) -- ACTIVATIONS ONLY:
//   h3 [0,16384)     xor32  (P3->P4), overlays h1/h0 (dead by P3 epilogue)
//   h1 [0,4096)      xor8   (P1->P2)
//   h0 [4096,6144)   xor-col (gload_lds pre-swizzled, ->P1)
//   h2 [16384,24576) xor16  (P2->P3); float scratch reuses this after P4
// Weights W1..W4 never touch LDS: each wave's B-fragment rows are private,
// loaded global->VGPR, dist-2 pipeline pinned by per-round vmcnt fences.
__global__ __launch_bounds__(256, 3)
void modules_fused(const bf16* __restrict__ h0g,
                   const bf16* __restrict__ W1b, const float* __restrict__ b1,
                   const bf16* __restrict__ W2b, const float* __restrict__ b2,
                   const bf16* __restrict__ W3b, const float* __restrict__ b3,
                   const bf16* __restrict__ W4b, const float* __restrict__ b4,
                   const float* __restrict__ Wout, const float* __restrict__ bout,
                   float* __restrict__ out) {
    constexpr int H3 = 0, H1 = 0, H0 = 4096, H2 = 16384;
    __shared__ __align__(16) bf16 pool[24576];

    const int tid = threadIdx.x, w = tid >> 6, lane = tid & 63;
    const int q = lane >> 4, ln = lane & 15;
    const int lr = lane >> 2, lk = lane & 3;
    const int swz = (lk ^ (lr & 3)) * 8;
    const int m = blockIdx.y;
    const int r0 = blockIdx.x * 64;

    const bf16* W1m = W1b + (size_t)m * 64 * 32;
    const bf16* W2m = W2b + (size_t)m * 128 * 64;
    const bf16* W3m = W3b + (size_t)m * 256 * 128;
    const bf16* W4m = W4b + (size_t)m * 512 * 256;

    // XOR-chunk activation layout: elem = row*nch*8 + ((chunk^(row&7))*8)+sub.
    // For b128 fragment reads (16 ln-rows x 4 q-slots) this gives the wave64
    // minimum of 8 lanes per 4-bank group (conflict-free for ds_read_b128).
    auto rdX = [&](int base, int nch, int row, int chunk) -> bf16x8 {
        return *(const bf16x8*)&pool[base + row * nch * 8 + ((chunk ^ (row & 7)) * 8)];
    };
    auto rdA0 = [&](int row) -> bf16x8 {   // h0: gload pre-swizzle layout
        return *(const bf16x8*)&pool[H0 + row * 32 + ((q ^ (row & 3)) * 8)];
    };
    auto wrX = [&](int base, int nch, int row, int col, float v) {
        pool[base + row * nch * 8 + (((col >> 3) ^ (row & 7)) * 8) + (col & 7)] =
            __float2bfloat16(v);
    };
    // weight B-fragment straight from global: lane(q,ln) gets W[row][kc*8..+8]
    auto ldW = [&](const bf16* Wm, int ldg, int row, int kc) -> bf16x8 {
        return *(const bf16x8*)&Wm[(size_t)row * ldg + kc * 8];
    };

    // ---- epilogue scalars (drained by the WAITV(0) below)
    float b1v = b1[m * 64 + w * 16 + ln];
    float b2v[2], b3v[2][2], b4v[4][2], wov[4][2];
#pragma unroll
    for (int j = 0; j < 2; ++j) b2v[j] = b2[m * 128 + w * 32 + j * 16 + ln];
#pragma unroll
    for (int oc = 0; oc < 2; ++oc)
#pragma unroll
        for (int j = 0; j < 2; ++j)
            b3v[oc][j] = b3[m * 256 + oc * 128 + w * 32 + j * 16 + ln];
#pragma unroll
    for (int nc = 0; nc < 4; ++nc)
#pragma unroll
        for (int j = 0; j < 2; ++j) {
            int col = nc * 128 + w * 32 + j * 16 + ln;
            b4v[nc][j] = b4[(size_t)m * 512 + col];
            wov[nc][j] = Wout[(size_t)m * 512 + col];
        }
    float boutv = bout[m];

    // ---- h0 strip -> LDS (the only shared input); W1/W2 + W3 r0,r1 -> regs
    gload16_lds(h0g + (size_t)(r0 + w * 16 + lr) * 4096 + m * 32 + swz,
                pool + H0 + w * 512);
    bf16x8 f1 = ldW(W1m, 32, w * 16 + ln, q);
    bf16x8 f2[2][2], f3[2][2], f4[2][2];
#pragma unroll
    for (int kk = 0; kk < 2; ++kk)
#pragma unroll
        for (int j = 0; j < 2; ++j)
            f2[kk][j] = ldW(W2m, 64, w * 32 + j * 16 + ln, kk * 4 + q);
#pragma unroll
    for (int p = 0; p < 2; ++p)
#pragma unroll
        for (int j = 0; j < 2; ++j)
            f3[p][j] = ldW(W3m, 128, w * 32 + j * 16 + ln, p * 4 + q);
    WAITV(0);
    BAR();   // h0 visible to all waves

    // ================= P1: h1 = relu(h0 @ W1^T + b1) =================
    {
        f32x4 a1[4];
#pragma unroll
        for (int i = 0; i < 4; ++i) {
            a1[i] = (f32x4){0.f, 0.f, 0.f, 0.f};
            a1[i] = __builtin_amdgcn_mfma_f32_16x16x32_bf16(rdA0(i * 16 + ln), f1,
                                                            a1[i], 0, 0, 0);
        }
#pragma unroll
        for (int i = 0; i < 4; ++i)
#pragma unroll
            for (int rr = 0; rr < 4; ++rr) {
                float v = a1[i][rr] + b1v;
                wrX(H1, 8, i * 16 + q * 4 + rr, w * 16 + ln, v > 0.f ? v : 0.f);
            }
        WAITL();
        BAR();   // h1 visible
    }

    // ================= P2: h2 = relu(h1 @ W2^T + b2) =================
    {
        f32x4 a2[4][2];
#pragma unroll
        for (int i = 0; i < 4; ++i)
#pragma unroll
            for (int j = 0; j < 2; ++j) a2[i][j] = (f32x4){0.f, 0.f, 0.f, 0.f};
#pragma unroll
        for (int kk = 0; kk < 2; ++kk) {
            bf16x8 aF[4];
#pragma unroll
            for (int i = 0; i < 4; ++i) aF[i] = rdX(H1, 8, i * 16 + ln, kk * 4 + q);
#pragma unroll
            for (int i = 0; i < 4; ++i)
#pragma unroll
                for (int j = 0; j < 2; ++j)
                    a2[i][j] = __builtin_amdgcn_mfma_f32_16x16x32_bf16(
                        aF[i], f2[kk][j], a2[i][j], 0, 0, 0);
        }
#pragma unroll
        for (int j = 0; j < 2; ++j)
#pragma unroll
            for (int i = 0; i < 4; ++i)
#pragma unroll
                for (int rr = 0; rr < 4; ++rr) {
                    float v = a2[i][j][rr] + b2v[j];
                    wrX(H2, 16, i * 16 + q * 4 + rr, w * 32 + j * 16 + ln,
                        v > 0.f ? v : 0.f);
                }
        WAITL();
        BAR();   // h2 visible
    }

    // ===== P3: h3 = relu(h2 @ W3^T + b3); W3 reg-stream dist-2 =====
    // Per-round fence pins the pipeline: round r needs pf(r) done, leaves
    // pf(r+1) (one 2-load group) in flight -> vmcnt(2). Rounds 0,1 consume
    // the pre-drained prime; compiler fence only. Last round drains.
#pragma unroll
    for (int oc = 0; oc < 2; ++oc) {
        f32x4 a3[4][2];
#pragma unroll
        for (int i = 0; i < 4; ++i)
#pragma unroll
            for (int j = 0; j < 2; ++j) a3[i][j] = (f32x4){0.f, 0.f, 0.f, 0.f};
#pragma unroll
        for (int kr = 0; kr < 4; ++kr) {
            const int r = oc * 4 + kr, p = r & 1;
            if (r < 2)       CFENCE();
            else if (r < 7)  WAITV(2);
            else             WAITV(0);
            bf16x8 c0 = f3[p][0], c1 = f3[p][1];
            if (r + 2 < 8) {
                const int r2 = r + 2;
#pragma unroll
                for (int j = 0; j < 2; ++j)
                    f3[p][j] = ldW(W3m, 128,
                                   (r2 >> 2) * 128 + w * 32 + j * 16 + ln,
                                   (r2 & 3) * 4 + q);
            }
            bf16x8 aF[4];
#pragma unroll
            for (int i = 0; i < 4; ++i) aF[i] = rdX(H2, 16, i * 16 + ln, kr * 4 + q);
#pragma unroll
            for (int i = 0; i < 4; ++i) {
                a3[i][0] = __builtin_amdgcn_mfma_f32_16x16x32_bf16(aF[i], c0,
                                                                   a3[i][0], 0, 0, 0);
                a3[i][1] = __builtin_amdgcn_mfma_f32_16x16x32_bf16(aF[i], c1,
                                                                   a3[i][1], 0, 0, 0);
            }
        }
#pragma unroll
        for (int j = 0; j < 2; ++j)
#pragma unroll
            for (int i = 0; i < 4; ++i)
#pragma unroll
                for (int rr = 0; rr < 4; ++rr) {
                    float v = a3[i][j][rr] + b3v[oc][j];
                    wrX(H3, 32, i * 16 + q * 4 + rr,
                        oc * 128 + w * 32 + j * 16 + ln, v > 0.f ? v : 0.f);
                }
    }
    // prime W4 rounds 0,1 (VGPR dest: safe to stay in flight across the bar)
#pragma unroll
    for (int p = 0; p < 2; ++p)
#pragma unroll
        for (int j = 0; j < 2; ++j)
            f4[p][j] = ldW(W4m, 256, w * 32 + j * 16 + ln, p * 4 + q);
    WAITL();
    BAR();   // h3 visible; h2 dead for all waves

    // == P4: L4 (4 nc-chunks of 128 cols) + Wout dot; dist-2, fenced rounds ==
    float pl[4][4];
#pragma unroll
    for (int i = 0; i < 4; ++i)
#pragma unroll
        for (int rr = 0; rr < 4; ++rr) pl[i][rr] = 0.f;

#pragma unroll
    for (int nc = 0; nc < 4; ++nc) {
        f32x4 a4[4][2];
#pragma unroll
        for (int i = 0; i < 4; ++i)
#pragma unroll
            for (int j = 0; j < 2; ++j) a4[i][j] = (f32x4){0.f, 0.f, 0.f, 0.f};
#pragma unroll
        for (int kr = 0; kr < 8; ++kr) {
            const int r = nc * 8 + kr, p = r & 1;
            if (r < 31) WAITV(2); else WAITV(0);   // pf(r) done, pf(r+1) flying
            bf16x8 c0 = f4[p][0], c1 = f4[p][1];
            if (r + 2 < 32) {
                const int r2 = r + 2;
#pragma unroll
                for (int j = 0; j < 2; ++j)
                    f4[p][j] = ldW(W4m, 256,
                                   (r2 >> 3) * 128 + w * 32 + j * 16 + ln,
                                   (r2 & 7) * 4 + q);
            }
            bf16x8 aF[4];
#pragma unroll
            for (int i = 0; i < 4; ++i) aF[i] = rdX(H3, 32, i * 16 + ln, kr * 4 + q);
#pragma unroll
            for (int i = 0; i < 4; ++i) {
                a4[i][0] = __builtin_amdgcn_mfma_f32_16x16x32_bf16(aF[i], c0,
                                                                   a4[i][0], 0, 0, 0);
                a4[i][1] = __builtin_amdgcn_mfma_f32_16x16x32_bf16(aF[i], c1,
                                                                   a4[i][1], 0, 0, 0);
            }
        }
#pragma unroll
        for (int j = 0; j < 2; ++j) {
            float bb = b4v[nc][j], wv = wov[nc][j];
#pragma unroll
            for (int i = 0; i < 4; ++i)
#pragma unroll
                for (int rr = 0; rr < 4; ++rr) {
                    float v = a4[i][j][rr] + bb;
                    v = v > 0.f ? v : 0.f;
                    pl[i][rr] += v * wv;
                }
        }
    }

    // ---- reduce: 16 col-lanes via shuffle, 4 waves via LDS, sigmoid store ----
    // scratch over dead h2 [16384..): lagging waves only read h3 [0,16384).
    float* sc = (float*)&pool[H2];
#pragma unroll
    for (int i = 0; i < 4; ++i)
#pragma unroll
        for (int rr = 0; rr < 4; ++rr) {
            float p = pl[i][rr];
            p += __shfl_xor(p, 1);
            p += __shfl_xor(p, 2);
            p += __shfl_xor(p, 4);
            p += __shfl_xor(p, 8);
            if (ln == 0) sc[w * 64 + i * 16 + q * 4 + rr] = p;
        }
    __syncthreads();
    if (tid < 64) {
        float s = sc[tid] + sc[64 + tid] + sc[128 + tid] + sc[192 + tid];
        float lg = s + boutv;
        out[(size_t)(r0 + tid) * M_ + m] = 1.f / (1.f + __expf(-lg));
    }
}

// ---------------- host ----------------
extern "C" void kernel_launch(void* const* d_in, const int* in_sizes, int n_in,
                              void* d_out, int out_size, void* d_ws, size_t ws_size,
                              hipStream_t stream) {
    const float* x    = (const float*)d_in[0];
    const float* W0   = (const float*)d_in[1];
    const float* b0   = (const float*)d_in[2];
    const float* W1   = (const float*)d_in[3];
    const float* b1   = (const float*)d_in[4];
    const float* W2   = (const float*)d_in[5];
    const float* b2   = (const float*)d_in[6];
    const float* W3   = (const float*)d_in[7];
    const float* b3   = (const float*)d_in[8];
    const float* W4   = (const float*)d_in[9];
    const float* b4   = (const float*)d_in[10];
    const float* Wout = (const float*)d_in[11];
    const float* bout = (const float*)d_in[12];
    float* out = (float*)d_out;

    char* ws = (char*)d_ws;
    size_t off = 0;
    auto alloc = [&](size_t bytes) -> void* {
        off = (off + 255) & ~(size_t)255;
        void* p = ws + off;
        off += bytes;
        return p;
    };
    bf16* W0b = (bf16*)alloc((size_t)4096 * 4096 * 2);
    bf16* W1b = (bf16*)alloc((size_t)M_ * 64 * 32 * 2);
    bf16* W2b = (bf16*)alloc((size_t)M_ * 128 * 64 * 2);
    bf16* W3b = (bf16*)alloc((size_t)M_ * 256 * 128 * 2);
    bf16* W4b = (bf16*)alloc((size_t)M_ * 512 * 256 * 2);
    bf16* xb  = (bf16*)alloc((size_t)B_ * 4096 * 2);
    bf16* h0  = (bf16*)alloc((size_t)B_ * 4096 * 2);   // [B][128][32]

    CvtArgs ca;
    ca.src[0] = (const float4*)x;  ca.dst[0] = (short4*)xb;
    ca.src[1] = (const float4*)W0; ca.dst[1] = (short4*)W0b;
    ca.src[2] = (const float4*)W1; ca.dst[2] = (short4*)W1b;
    ca.src[3] = (const float4*)W2; ca.dst[3] = (short4*)W2b;
    ca.src[4] = (const float4*)W3; ca.dst[4] = (short4*)W3b;
    ca.src[5] = (const float4*)W4; ca.dst[5] = (short4*)W4b;
    cvt_all<<<(10813440 + 255) / 256, 256, 0, stream>>>(ca);

    {
        dim3 g(4096 / 64, B_ / 128, 1);
        gemm_l0<<<g, 256, 0, stream>>>(xb, W0b, b0, h0);
    }
    {
        dim3 g(B_ / 64, M_, 1);
        modules_fused<<<g, 256, 0, stream>>>(h0, W1b, b1, W2b, b2, W3b, b3,
                                             W4b, b4, Wout, bout, out);
    }
}